// Round 1
// baseline (866.782 us; speedup 1.0000x reference)
//
#include <hip/hip_runtime.h>
#include <stdint.h>

typedef __attribute__((ext_vector_type(8))) short short8;
typedef __attribute__((ext_vector_type(4))) float f32x4;

__device__ __forceinline__ unsigned short f2bf(float f){
  union{float f; unsigned u;} v; v.f = f;
  unsigned r = v.u + 0x7FFFu + ((v.u >> 16) & 1u);
  return (unsigned short)(r >> 16);
}
__device__ __forceinline__ float bf2f(unsigned short s){
  union{unsigned u; float f;} v; v.u = ((unsigned)s) << 16; return v.f;
}
__device__ __forceinline__ void dec8(uint4 d, float* r){
  union{unsigned a; float f;} t;
  t.a = (d.x & 0xFFFFu) << 16; r[0]=t.f; t.a = d.x & 0xFFFF0000u; r[1]=t.f;
  t.a = (d.y & 0xFFFFu) << 16; r[2]=t.f; t.a = d.y & 0xFFFF0000u; r[3]=t.f;
  t.a = (d.z & 0xFFFFu) << 16; r[4]=t.f; t.a = d.z & 0xFFFF0000u; r[5]=t.f;
  t.a = (d.w & 0xFFFFu) << 16; r[6]=t.f; t.a = d.w & 0xFFFF0000u; r[7]=t.f;
}

// Pack conv_w [128][64][3][3] -> wA [ks=18][m=128][kk=32] bf16, k = (dh*3+dw)*64 + cin
__global__ __launch_bounds__(256) void k_prep(const float* __restrict__ cw,
                                              unsigned short* __restrict__ wA){
  int i = blockIdx.x*256 + threadIdx.x;
  if(i >= 18*128*32) return;
  int kk = i & 31, m = (i >> 5) & 127, ks = i >> 12;
  int k = ks*32 + kk;
  int pos = k >> 6, cin = k & 63;
  int dh = pos/3, dw = pos - dh*3;
  wA[i] = f2bf(cw[((m*64 + cin)*3 + dh)*3 + dw]);
}

// Implicit-GEMM conv: block = (b, 2 output rows). M=128 cout x N=128 (2h x 64w), K=576.
// LDS x tile: [4 rows][64 w][72 cin-padded] bf16. Writes conv_raw bf16 + BN1 slot-stats.
__global__ __launch_bounds__(256) void k_conv(
    const float* __restrict__ x, const unsigned short* __restrict__ wA,
    unsigned short* __restrict__ craw, float* __restrict__ sum_slots,
    float* __restrict__ sq_slots)
{
  const int b = blockIdx.y;
  const int h0 = blockIdx.x * 2;
  __shared__ __align__(16) unsigned short xs[4*64*72];
  __shared__ float red[2][128];
  const int t = threadIdx.x;
  { // stage x (fp32->bf16, transpose to cin-innermost)
    const int l16 = t & 15, g = t >> 4;
    for(int i=0;i<16;++i){
      int p = g*16 + i;               // (row, cin) pair
      int r = p >> 6, cin = p & 63;
      int hin = h0 - 1 + r;
      hin = hin < 0 ? 1 : (hin > 511 ? 510 : hin);   // reflect pad
      const float* rowp = x + (((size_t)b*64 + cin)*512 + (size_t)hin)*64;
      int base = (r*64)*72 + cin;
      #pragma unroll
      for(int j=0;j<4;++j){
        int w = l16 + 16*j;
        xs[base + w*72] = f2bf(rowp[w]);
      }
    }
  }
  __syncthreads();
  const int lane = t & 63, wv = t >> 6;
  const int r15 = lane & 15, quad = lane >> 4;
  const int nbase = wv * 32;
  f32x4 acc[8][2];
  #pragma unroll
  for(int mt=0;mt<8;++mt){
    #pragma unroll
    for(int nt=0;nt<2;++nt){ f32x4 z = {0.f,0.f,0.f,0.f}; acc[mt][nt] = z; }
  }
  short8 a_cur[8], a_nxt[8];
  const unsigned short* wbase = wA + r15*32 + quad*8;
  #pragma unroll
  for(int mt=0;mt<8;++mt) a_cur[mt] = *(const short8*)(wbase + mt*512);
  for(int ks=0; ks<18; ++ks){
    if(ks < 17){
      const unsigned short* wk = wbase + (ks+1)*4096;
      #pragma unroll
      for(int mt=0;mt<8;++mt) a_nxt[mt] = *(const short8*)(wk + mt*512);
    }
    const int pos = ks >> 1;
    const int dh = pos/3, dw = pos - dh*3;
    const int cb = (ks & 1)*32 + quad*8;
    short8 bfr[2];
    #pragma unroll
    for(int nt=0;nt<2;++nt){
      int n = nbase + nt*16 + r15;
      int hr = n >> 6, w = n & 63;
      int wi = w + dw - 1;
      wi = wi < 0 ? 1 : (wi > 63 ? 62 : wi);   // reflect pad
      int rr = hr + dh;
      bfr[nt] = *(const short8*)&xs[(rr*64 + wi)*72 + cb];
    }
    #pragma unroll
    for(int mt=0;mt<8;++mt){
      acc[mt][0] = __builtin_amdgcn_mfma_f32_16x16x32_bf16(a_cur[mt], bfr[0], acc[mt][0], 0,0,0);
      acc[mt][1] = __builtin_amdgcn_mfma_f32_16x16x32_bf16(a_cur[mt], bfr[1], acc[mt][1], 0,0,0);
    }
    #pragma unroll
    for(int mt=0;mt<8;++mt) a_cur[mt] = a_nxt[mt];
  }
  // epilogue: store conv_raw bf16. D layout: col=lane&15 (n), row=quad*4+reg (m)
  #pragma unroll
  for(int nt=0;nt<2;++nt){
    int n = nbase + nt*16 + r15;
    int hr = n >> 6, w = n & 63;
    size_t obase = (((size_t)b*128)*512 + (size_t)(h0+hr))*64 + w;
    #pragma unroll
    for(int mt=0;mt<8;++mt){
      #pragma unroll
      for(int rg=0;rg<4;++rg){
        int co = mt*16 + quad*4 + rg;
        craw[obase + (size_t)co*32768] = f2bf(acc[mt][nt][rg]);
      }
    }
  }
  // BN1 stats: per-cout sum/sumsq, reduce within quad-lanes -> LDS -> slotted global atomics
  if(t < 128){ red[0][t] = 0.f; red[1][t] = 0.f; }
  __syncthreads();
  #pragma unroll
  for(int mt=0;mt<8;++mt){
    #pragma unroll
    for(int rg=0;rg<4;++rg){
      float v0 = acc[mt][0][rg], v1 = acc[mt][1][rg];
      float s = v0 + v1;
      float q = v0*v0 + v1*v1;
      #pragma unroll
      for(int m=1;m<16;m<<=1){ s += __shfl_xor(s, m); q += __shfl_xor(q, m); }
      if(r15 == 0){
        int co = mt*16 + quad*4 + rg;
        atomicAdd(&red[0][co], s);
        atomicAdd(&red[1][co], q);
      }
    }
  }
  __syncthreads();
  if(t < 128){
    int slot = blockIdx.x & 63;
    atomicAdd(&sum_slots[t*64 + slot], red[0][t]);
    atomicAdd(&sq_slots[t*64 + slot], red[1][t]);
  }
}

__global__ __launch_bounds__(256) void k_bn1fin(
    const float* __restrict__ sum_slots, const float* __restrict__ sq_slots,
    const float* __restrict__ g1, const float* __restrict__ b1,
    float* __restrict__ s1, float* __restrict__ t1)
{
  int c = threadIdx.x; if(c >= 128) return;
  double S = 0.0, Q = 0.0;
  for(int s=0;s<64;++s){ S += (double)sum_slots[c*64+s]; Q += (double)sq_slots[c*64+s]; }
  const double N = 524288.0;
  double mu = S/N, var = Q/N - mu*mu;
  float sc = (float)((double)g1[c] / sqrt(var + 1e-5));
  s1[c] = sc;
  t1[c] = (float)((double)b1[c] - mu*(double)sc);
}

// read conv_raw, h=relu(bn1), emit xm=mean_w(h), S_h/Q_h per channel, LN partials per batch
__global__ __launch_bounds__(256) void k_passB(
    const unsigned short* __restrict__ craw, const float* __restrict__ s1,
    const float* __restrict__ t1, float* __restrict__ xm,
    float* __restrict__ Sh, float* __restrict__ Qh,
    float* __restrict__ lnS, float* __restrict__ lnQ)
{
  const int c = blockIdx.x, b = blockIdx.y;
  const int t = threadIdx.x, wv = t >> 6, l = t & 63;
  const float sc = s1[c], sf = t1[c];
  const unsigned short* base = craw + (((size_t)b*128 + c)*512)*64;
  float* xrow = xm + ((size_t)b*128 + c)*512;
  float sa = 0.f, qa = 0.f, la = 0.f;
  for(int it=0; it<16; ++it){
    int row = it*32 + wv*8 + (l >> 3);
    int w0 = (l & 7)*8;
    uint4 d = *(const uint4*)(base + (size_t)row*64 + w0);
    float r[8]; dec8(d, r);
    float tot = 0.f;
    #pragma unroll
    for(int j=0;j<8;++j){
      float v = sc*r[j] + sf;
      v = v > 0.f ? v : 0.f;
      tot += v; sa += v; qa += v*v;
    }
    tot += __shfl_xor(tot, 1); tot += __shfl_xor(tot, 2); tot += __shfl_xor(tot, 4);
    if((l & 7) == 0){
      float mv = tot * (1.f/64.f);
      xrow[row] = mv;
      la += mv*mv;
    }
  }
  #pragma unroll
  for(int m=1;m<64;m<<=1){
    sa += __shfl_xor(sa, m); qa += __shfl_xor(qa, m); la += __shfl_xor(la, m);
  }
  __shared__ float rs[4], rq[4], rl[4];
  if(l == 0){ rs[wv]=sa; rq[wv]=qa; rl[wv]=la; }
  __syncthreads();
  if(t == 0){
    float S = rs[0]+rs[1]+rs[2]+rs[3];
    float Q = rq[0]+rq[1]+rq[2]+rq[3];
    float L = rl[0]+rl[1]+rl[2]+rl[3];
    atomicAdd(&Sh[c], S);
    atomicAdd(&Qh[c], Q);
    atomicAdd(&lnS[b], S * (1.f/64.f));
    atomicAdd(&lnQ[b], L);
  }
}

__global__ __launch_bounds__(256) void k_lnfin(
    const float* __restrict__ lnS, const float* __restrict__ lnQ,
    float* __restrict__ ln_mu, float* __restrict__ ln_rs)
{
  int b = threadIdx.x; if(b >= 16) return;
  double mu = (double)lnS[b] / 65536.0;
  double var = (double)lnQ[b] / 65536.0 - mu*mu;
  ln_mu[b] = (float)mu;
  ln_rs[b] = (float)(1.0 / sqrt(var + 1e-5));
}

__global__ __launch_bounds__(256) void k_xn(
    const float* __restrict__ xm, const float* __restrict__ ln_mu,
    const float* __restrict__ ln_rs, float* __restrict__ xn)
{
  int i = blockIdx.x*256 + threadIdx.x;
  if(i >= 16*128*512) return;
  int b = i >> 16;
  xn[i] = (xm[i] - ln_mu[b]) * ln_rs[b];
}

// scores f[b,h,k] = sum_c xn[b,c,h]*xn[b,c,k] / sqrt(128); 64x64 tile per block
__global__ __launch_bounds__(256) void k_f(const float* __restrict__ xn, float* __restrict__ f)
{
  const int kt = blockIdx.x, ht = blockIdx.y, b = blockIdx.z;
  __shared__ __align__(16) float Xh[128][64];
  __shared__ __align__(16) float Xk[128][64];
  const int t = threadIdx.x;
  const int h0 = ht*64, k0 = kt*64;
  for(int i=0;i<32;++i){
    int idx = t + i*256;
    int c = idx >> 6, hh = idx & 63;
    const float* src = xn + ((size_t)b*128 + c)*512;
    Xh[c][hh] = src[h0 + hh];
    Xk[c][hh] = src[k0 + hh];
  }
  __syncthreads();
  const int tx = t & 15, ty = t >> 4;
  float acc[4][4] = {{0}};
  for(int c=0;c<128;++c){
    f32x4 a = *(const f32x4*)&Xh[c][ty*4];
    f32x4 bb = *(const f32x4*)&Xk[c][tx*4];
    #pragma unroll
    for(int i=0;i<4;++i)
      #pragma unroll
      for(int j=0;j<4;++j) acc[i][j] += a[i]*bb[j];
  }
  const float s = 0.088388347648318447f;
  #pragma unroll
  for(int i=0;i<4;++i){
    f32x4 o;
    o[0]=acc[i][0]*s; o[1]=acc[i][1]*s; o[2]=acc[i][2]*s; o[3]=acc[i][3]*s;
    *(f32x4*)&f[((size_t)b*512 + h0 + ty*4 + i)*512 + k0 + tx*4] = o;
  }
}

// softmax over last axis, one row (512) per wave
__global__ __launch_bounds__(256) void k_sm(float* __restrict__ f)
{
  const int bid = blockIdx.x;
  const int b = bid >> 7, h4 = bid & 127;
  const int t = threadIdx.x, wv = t >> 6, l = t & 63;
  float* row = f + ((size_t)b*512 + h4*4 + wv)*512;
  f32x4 v0 = *(const f32x4*)&row[l*8];
  f32x4 v1 = *(const f32x4*)&row[l*8 + 4];
  float mx = v0[0];
  #pragma unroll
  for(int j=1;j<4;++j) mx = fmaxf(mx, v0[j]);
  #pragma unroll
  for(int j=0;j<4;++j) mx = fmaxf(mx, v1[j]);
  #pragma unroll
  for(int m=1;m<64;m<<=1) mx = fmaxf(mx, __shfl_xor(mx, m));
  float sum = 0.f;
  #pragma unroll
  for(int j=0;j<4;++j){ v0[j] = __expf(v0[j]-mx); sum += v0[j]; }
  #pragma unroll
  for(int j=0;j<4;++j){ v1[j] = __expf(v1[j]-mx); sum += v1[j]; }
  #pragma unroll
  for(int m=1;m<64;m<<=1) sum += __shfl_xor(sum, m);
  float inv = 1.f / sum;
  #pragma unroll
  for(int j=0;j<4;++j){ v0[j] *= inv; v1[j] *= inv; }
  *(f32x4*)&row[l*8] = v0;
  *(f32x4*)&row[l*8+4] = v1;
}

// y1[b,m,k] = sum_c g_w[m,c]*xn[b,c,k] + g_b[m]; block = (64-k tile, b), all 128 m
__global__ __launch_bounds__(256) void k_y1(
    const float* __restrict__ xn, const float* __restrict__ gw,
    const float* __restrict__ gb, float* __restrict__ y1)
{
  const int kt = blockIdx.x, b = blockIdx.y;
  __shared__ __align__(16) float GT[128][128];
  __shared__ __align__(16) float XN[128][68];
  const int t = threadIdx.x;
  const int k0 = kt*64;
  for(int i=0;i<64;++i){
    int idx = t + i*256;
    int o = idx & 127, c = idx >> 7;
    GT[c][o] = gw[o*128 + c];
  }
  for(int i=0;i<32;++i){
    int idx = t + i*256;
    int c = idx >> 6, kk = idx & 63;
    XN[c][kk] = xn[((size_t)b*128 + c)*512 + k0 + kk];
  }
  __syncthreads();
  const int tx = t & 15, ty = t >> 4;
  float acc[8][4] = {{0}};
  for(int c=0;c<128;++c){
    f32x4 a0 = *(const f32x4*)&GT[c][ty*8];
    f32x4 a1 = *(const f32x4*)&GT[c][ty*8+4];
    f32x4 bv = *(const f32x4*)&XN[c][tx*4];
    #pragma unroll
    for(int j=0;j<4;++j){
      #pragma unroll
      for(int i=0;i<4;++i){ acc[i][j] += a0[i]*bv[j]; acc[i+4][j] += a1[i]*bv[j]; }
    }
  }
  #pragma unroll
  for(int i=0;i<8;++i){
    int m = ty*8 + i;
    float bias = gb[m];
    f32x4 o;
    #pragma unroll
    for(int j=0;j<4;++j) o[j] = acc[i][j] + bias;
    *(f32x4*)&y1[((size_t)b*128 + m)*512 + k0 + tx*4] = o;
  }
}

// y2t[b,h,m] = sum_k f[b,h,k]*y1[b,m,k]; block = (32-h tile, b), K=512 chunked by 64
__global__ __launch_bounds__(256) void k_y2(
    const float* __restrict__ f, const float* __restrict__ y1,
    float* __restrict__ y2t)
{
  const int ht = blockIdx.x, b = blockIdx.y;
  __shared__ __align__(16) float FT[64][36];
  __shared__ __align__(16) float Y1T[64][132];
  const int t = threadIdx.x;
  const int h0 = ht*32;
  const int tx = t & 15, ty = t >> 4;
  float acc[2][8] = {{0}};
  for(int kc=0;kc<8;++kc){
    int k0 = kc*64;
    __syncthreads();
    for(int i=0;i<8;++i){
      int idx = t + i*256;
      int k = idx & 63, hh = idx >> 6;
      FT[k][hh] = f[((size_t)b*512 + h0 + hh)*512 + k0 + k];
    }
    for(int i=0;i<32;++i){
      int idx = t + i*256;
      int k = idx & 63, m = idx >> 6;
      Y1T[k][m] = y1[((size_t)b*128 + m)*512 + k0 + k];
    }
    __syncthreads();
    for(int kk=0;kk<64;++kk){
      float a0 = FT[kk][ty*2], a1 = FT[kk][ty*2+1];
      f32x4 b0 = *(const f32x4*)&Y1T[kk][tx*8];
      f32x4 b1 = *(const f32x4*)&Y1T[kk][tx*8+4];
      #pragma unroll
      for(int j=0;j<4;++j){
        acc[0][j]   += a0*b0[j]; acc[1][j]   += a1*b0[j];
        acc[0][j+4] += a0*b1[j]; acc[1][j+4] += a1*b1[j];
      }
    }
  }
  #pragma unroll
  for(int i=0;i<2;++i){
    int h = h0 + ty*2 + i;
    f32x4 o0, o1;
    #pragma unroll
    for(int j=0;j<4;++j){ o0[j]=acc[i][j]; o1[j]=acc[i][j+4]; }
    float* dst = y2t + ((size_t)b*512 + h)*128 + tx*8;
    *(f32x4*)dst = o0;
    *(f32x4*)(dst+4) = o1;
  }
}

// y3[b,o,h] = sum_m out_w[o,m]*y2t[b,h,m] + out_b[o]; block = (32-h tile, b)
__global__ __launch_bounds__(256) void k_y3(
    const float* __restrict__ y2t, const float* __restrict__ ow,
    const float* __restrict__ obv, float* __restrict__ y3)
{
  const int ht = blockIdx.x, b = blockIdx.y;
  __shared__ __align__(16) float WT[128][128];
  __shared__ __align__(16) float Y2[128][36];
  const int t = threadIdx.x;
  const int h0 = ht*32;
  for(int i=0;i<64;++i){
    int idx = t + i*256;
    int o = idx & 127, m = idx >> 7;
    WT[m][o] = ow[o*128 + m];
  }
  for(int i=0;i<16;++i){
    int idx = t + i*256;
    int m = idx & 127, hh = idx >> 7;
    Y2[m][hh] = y2t[((size_t)b*512 + h0 + hh)*128 + m];
  }
  __syncthreads();
  const int tx = t & 15, ty = t >> 4;
  float acc[8][2] = {{0}};
  for(int m=0;m<128;++m){
    f32x4 a0 = *(const f32x4*)&WT[m][ty*8];
    f32x4 a1 = *(const f32x4*)&WT[m][ty*8+4];
    float b0 = Y2[m][tx*2], b1 = Y2[m][tx*2+1];
    #pragma unroll
    for(int i=0;i<4;++i){
      acc[i][0]   += a0[i]*b0; acc[i][1]   += a0[i]*b1;
      acc[i+4][0] += a1[i]*b0; acc[i+4][1] += a1[i]*b1;
    }
  }
  #pragma unroll
  for(int i=0;i<8;++i){
    int o = ty*8 + i;
    float bias = obv[o];
    float2 v; v.x = acc[i][0] + bias; v.y = acc[i][1] + bias;
    *(float2*)&y3[((size_t)b*128 + o)*512 + h0 + tx*2] = v;
  }
}

// per-channel sums of y3, y3^2, y3*xm (one block per channel, deterministic)
__global__ __launch_bounds__(256) void k_ystats(
    const float* __restrict__ y3, const float* __restrict__ xm,
    float* __restrict__ Sy, float* __restrict__ Syy, float* __restrict__ Sxy)
{
  const int c = blockIdx.x;
  const int t = threadIdx.x, wv = t >> 6, l = t & 63;
  float s=0.f, ss=0.f, sx=0.f;
  for(int i=0;i<32;++i){
    int idx = t + i*256;
    int b = idx >> 9, h = idx & 511;
    size_t off = ((size_t)b*128 + c)*512 + h;
    float v = y3[off], u = xm[off];
    s += v; ss += v*v; sx += v*u;
  }
  #pragma unroll
  for(int m=1;m<64;m<<=1){ s += __shfl_xor(s,m); ss += __shfl_xor(ss,m); sx += __shfl_xor(sx,m); }
  __shared__ float r1[4], r2[4], r3[4];
  if(l == 0){ r1[wv]=s; r2[wv]=ss; r3[wv]=sx; }
  __syncthreads();
  if(t == 0){
    Sy[c]  = r1[0]+r1[1]+r1[2]+r1[3];
    Syy[c] = r2[0]+r2[1]+r2[2]+r2[3];
    Sxy[c] = r3[0]+r3[1]+r3[2]+r3[3];
  }
}

// BN2 stats via decomposition: S2 = Sh + W*Sy ; Q2 = Qh + 2W*Sxy + W*Syy
__global__ __launch_bounds__(256) void k_bn2fin(
    const float* __restrict__ Sh, const float* __restrict__ Qh,
    const float* __restrict__ Sy, const float* __restrict__ Syy,
    const float* __restrict__ Sxy, const float* __restrict__ g2,
    const float* __restrict__ b2, float* __restrict__ s2, float* __restrict__ t2)
{
  int c = threadIdx.x; if(c >= 128) return;
  const double N = 524288.0;
  double S2 = (double)Sh[c] + 64.0*(double)Sy[c];
  double Q2 = (double)Qh[c] + 128.0*(double)Sxy[c] + 64.0*(double)Syy[c];
  double mu = S2/N, var = Q2/N - mu*mu;
  float sc = (float)((double)g2[c] / sqrt(var + 1e-5));
  s2[c] = sc;
  t2[c] = (float)((double)b2[c] - mu*(double)sc);
}

// out = silu(bn2(relu(bn1(conv)) + y3))
__global__ __launch_bounds__(256) void k_final(
    const unsigned short* __restrict__ craw, const float* __restrict__ s1,
    const float* __restrict__ t1, const float* __restrict__ y3,
    const float* __restrict__ s2, const float* __restrict__ t2,
    float* __restrict__ out)
{
  const int c = blockIdx.x, b = blockIdx.y;
  const int t = threadIdx.x, wv = t >> 6, l = t & 63;
  const float a1 = s1[c], c1 = t1[c], a2 = s2[c], c2 = t2[c];
  const size_t rb = ((size_t)b*128 + c)*512;
  const unsigned short* base = craw + rb*64;
  const float* yrow = y3 + rb;
  float* ob = out + rb*64;
  for(int it=0; it<16; ++it){
    int row = it*32 + wv*8 + (l >> 3);
    int w0 = (l & 7)*8;
    uint4 d = *(const uint4*)(base + (size_t)row*64 + w0);
    float yv = yrow[row];
    float r[8]; dec8(d, r);
    f32x4 o0, o1;
    #pragma unroll
    for(int j=0;j<8;++j){
      float h = a1*r[j] + c1; h = h > 0.f ? h : 0.f;
      float z = a2*(h + yv) + c2;
      float val = z / (1.f + __expf(-z));
      if(j < 4) o0[j] = val; else o1[j-4] = val;
    }
    *(f32x4*)(ob + (size_t)row*64 + w0) = o0;
    *(f32x4*)(ob + (size_t)row*64 + w0 + 4) = o1;
  }
}

extern "C" void kernel_launch(void* const* d_in, const int* in_sizes, int n_in,
                              void* d_out, int out_size, void* d_ws, size_t ws_size,
                              hipStream_t stream)
{
  const float* x      = (const float*)d_in[0];
  const float* conv_w = (const float*)d_in[1];
  const float* bn1_g  = (const float*)d_in[2];
  const float* bn1_b  = (const float*)d_in[3];
  const float* g_w    = (const float*)d_in[4];
  const float* g_b    = (const float*)d_in[5];
  const float* out_w  = (const float*)d_in[6];
  const float* out_b  = (const float*)d_in[7];
  const float* bn2_g  = (const float*)d_in[8];
  const float* bn2_b  = (const float*)d_in[9];
  float* out = (float*)d_out;
  char* ws = (char*)d_ws;

  // ws layout (needs ~138.7 MB)
  float* sum_slots = (float*)(ws);            // 128*64
  float* sq_slots  = (float*)(ws + 32768);    // 128*64
  float* Sh        = (float*)(ws + 65536);    // 128
  float* Qh        = (float*)(ws + 66048);    // 128
  float* lnS       = (float*)(ws + 66560);    // 16
  float* lnQ       = (float*)(ws + 66624);    // 16  -- zero region ends at 66688
  float* s1        = (float*)(ws + 66688);
  float* t1        = (float*)(ws + 67200);
  float* ln_mu     = (float*)(ws + 67712);
  float* ln_rs     = (float*)(ws + 67776);
  float* Sy        = (float*)(ws + 67840);
  float* Syy       = (float*)(ws + 68352);
  float* Sxy       = (float*)(ws + 68864);
  float* s2        = (float*)(ws + 69376);
  float* t2        = (float*)(ws + 69888);
  unsigned short* wA = (unsigned short*)(ws + 70400);      // 147456 B
  float* y3        = (float*)(ws + 217856);                // 4 MB
  unsigned short* craw = (unsigned short*)(ws + 4412160);  // 134217728 B

  // intermediates that die before k_final live in d_out (268 MB) as scratch
  float* xm  = out;                 // 1M floats
  float* xn  = out + (1u<<20);
  float* y1  = out + 2*(1u<<20);
  float* y2t = out + 3*(1u<<20);
  float* f   = out + 4*(1u<<20);    // 4M floats

  hipMemsetAsync(ws, 0, 66688, stream);
  hipLaunchKernelGGL(k_prep,   dim3(288),      dim3(256), 0, stream, conv_w, wA);
  hipLaunchKernelGGL(k_conv,   dim3(256,16),   dim3(256), 0, stream, x, wA, craw, sum_slots, sq_slots);
  hipLaunchKernelGGL(k_bn1fin, dim3(1),        dim3(128), 0, stream, sum_slots, sq_slots, bn1_g, bn1_b, s1, t1);
  hipLaunchKernelGGL(k_passB,  dim3(128,16),   dim3(256), 0, stream, craw, s1, t1, xm, Sh, Qh, lnS, lnQ);
  hipLaunchKernelGGL(k_lnfin,  dim3(1),        dim3(64),  0, stream, lnS, lnQ, ln_mu, ln_rs);
  hipLaunchKernelGGL(k_xn,     dim3(4096),     dim3(256), 0, stream, xm, ln_mu, ln_rs, xn);
  hipLaunchKernelGGL(k_f,      dim3(8,8,16),   dim3(256), 0, stream, xn, f);
  hipLaunchKernelGGL(k_sm,     dim3(2048),     dim3(256), 0, stream, f);
  hipLaunchKernelGGL(k_y1,     dim3(8,16),     dim3(256), 0, stream, xn, g_w, g_b, y1);
  hipLaunchKernelGGL(k_y2,     dim3(16,16),    dim3(256), 0, stream, f, y1, y2t);
  hipLaunchKernelGGL(k_y3,     dim3(16,16),    dim3(256), 0, stream, y2t, out_w, out_b, y3);
  hipLaunchKernelGGL(k_ystats, dim3(128),      dim3(256), 0, stream, y3, xm, Sy, Syy, Sxy);
  hipLaunchKernelGGL(k_bn2fin, dim3(1),        dim3(128), 0, stream, Sh, Qh, Sy, Syy, Sxy, bn2_g, bn2_b, s2, t2);
  hipLaunchKernelGGL(k_final,  dim3(128,16),   dim3(256), 0, stream, craw, s1, t1, y3, s2, t2, out);
}